// Round 11
// baseline (18.537 us; speedup 1.0000x reference)
//
#include <hip/hip_runtime.h>

// ConvTranspose3d-via-FFT == circular 3^3 conv on 2x-upsampled grid.
// Parity decomposition (verified): out[b,i,2q+p] = sum_{j,t} We_p[i][j][t] * x[b,j,(q-t) mod 16]
//   p=0: t0 <- k0,    t1 <- k1+k2
//   p=1: t0 <- k0+k1, t1 <- k2     (per axis, circular mod 16)
//
// Round 11: self-sufficient blocks (no grid sync). Main block = (pd,ph) x
// 2 q-tiles; stages We panel (64KB) + its own x-region (80KB: 4b x 64j x
// 2dd x 5hh x 16ww) into 144KB LDS via global_load_lds(16B). 256 blocks x
// 256 thr = 1 block/CU, single round; wave = batch, 2 tiles x 2 pw accs.

typedef float f32x16 __attribute__((ext_vector_type(16)));
typedef short s16x8 __attribute__((ext_vector_type(8)));

#define CI  64
#define CO  32
#define QV  4096                     // 16^3
#define XT_ELEMS (4 * QV * CI)       // 1048576 bf16
// WeG layout: [pp=4][plane=16][chunk=8][i=32][e=8] bf16 ; plane = pw*8 + t
#define WE_PP    (16 * 8 * 32 * 8)   // 32768 elems = 64KB per (pd,ph)
#define WE_BYTES 65536
#define X_BYTES  81920               // 32bc x 10dhh x 16ww x 16B
#define LDS_BYTES (WE_BYTES + X_BYTES)   // 147456 <= 163840

__device__ __forceinline__ unsigned short f32_to_bf16_rne(float f) {
    union { float f; unsigned u; } v; v.f = f;
    unsigned u = v.u;
    unsigned r = u + 0x7FFFu + ((u >> 16) & 1u);
    return (unsigned short)(r >> 16);
}

__device__ __forceinline__ void gload_lds16(const void* g, void* l) {
    __builtin_amdgcn_global_load_lds(
        (__attribute__((address_space(1))) unsigned int*)g,
        (__attribute__((address_space(3))) unsigned int*)l, 16, 0, 0);
}

// ---- prep (verified R9): transpose x -> xT2[b][c][q][e] bf16; lanes<32
//      build WeG ----
__global__ __launch_bounds__(256)
void prep_kernel(const float* __restrict__ x, const float* __restrict__ weight,
                 unsigned short* __restrict__ xT, unsigned short* __restrict__ WeG) {
    const int blk = blockIdx.x;
    {
        const int tid = blk * 256 + threadIdx.x;        // 131072: (b, c, q)
        const int b  = tid >> 15;
        const int rem = tid & 32767;
        const int c  = rem >> 12;                        // j-chunk
        const int q  = rem & 4095;                       // lane-consecutive
        const float* xb = x + b * (CI * QV) + q;
        s16x8 pk;
        #pragma unroll
        for (int e = 0; e < 8; ++e)
            pk[e] = (short)f32_to_bf16_rne(xb[(c * 8 + e) * QV]);
        *reinterpret_cast<s16x8*>(xT + (((size_t)(b * 8 + c)) * QV + q) * 8) = pk;
    }
    if (threadIdx.x < 32) {
        const int tid = blk * 32 + threadIdx.x;          // 16384: p*2048+i*64+j
        const int p = tid >> 11, i = (tid >> 6) & 31, j = tid & 63;
        const int pd = p >> 2, ph = (p >> 1) & 1, pw = p & 1;
        const int pp = pd * 2 + ph;

        const float* wp = weight + (i * CI + j) * 27;
        float wv[27];
        #pragma unroll
        for (int k = 0; k < 27; ++k) wv[k] = wp[k];

        float t1[2][9];
        #pragma unroll
        for (int m = 0; m < 9; ++m) {
            t1[0][m] = pd ? (wv[m] + wv[9 + m]) : wv[m];
            t1[1][m] = pd ? wv[18 + m] : (wv[9 + m] + wv[18 + m]);
        }
        float t2[2][2][3];
        #pragma unroll
        for (int td = 0; td < 2; ++td)
            #pragma unroll
            for (int m = 0; m < 3; ++m) {
                t2[td][0][m] = ph ? (t1[td][m] + t1[td][3 + m]) : t1[td][m];
                t2[td][1][m] = ph ? (t1[td][6 + m]) : (t1[td][3 + m] + t1[td][6 + m]);
            }

        const int c = j >> 3, e = j & 7;
        #pragma unroll
        for (int td = 0; td < 2; ++td)
            #pragma unroll
            for (int th = 0; th < 2; ++th) {
                float a0 = pw ? (t2[td][th][0] + t2[td][th][1]) : t2[td][th][0];
                float a1 = pw ? t2[td][th][2] : (t2[td][th][1] + t2[td][th][2]);
                const int tA = td * 4 + th * 2;          // tw=0
                const int plane0 = pw * 8 + tA;
                WeG[(((pp * 16 + plane0) * 8 + c) * 32 + i) * 8 + e]     = f32_to_bf16_rne(a0);
                WeG[(((pp * 16 + plane0 + 1) * 8 + c) * 32 + i) * 8 + e] = f32_to_bf16_rne(a1);
            }
    }
}

// ---- main: 256 blocks x 256 threads; block = (pd,ph) x 2 q-tiles ----
__global__ __launch_bounds__(256)
void convt3d_mfma_kernel(const unsigned short* __restrict__ xT,
                         const unsigned short* __restrict__ WeG,
                         float* __restrict__ out) {
    __shared__ __align__(16) char smem[LDS_BYTES];
    unsigned short* we_lds = (unsigned short*)smem;          // 64KB
    char* x_lds = smem + WE_BYTES;                           // 80KB: [bc32][dhh10][ww16][e8]

    const int blk = blockIdx.x;          // 256
    const int pp  = blk >> 6;            // (pd,ph)
    const int T2  = blk & 63;            // (qd, qh-quad)
    const int pd = pp >> 1, ph = pp & 1;
    const int qd = T2 >> 2, qhq = T2 & 3;

    const int w    = threadIdx.x >> 6;
    const int lane = threadIdx.x & 63;

    // ---- stage We panel: 64 chunks of 1KB (contiguous src & dst) ----
    {
        const char* src = (const char*)(WeG + pp * WE_PP);
        #pragma unroll
        for (int k = 0; k < 16; ++k) {
            const int off = (w * 16 + k) * 1024 + lane * 16;
            gload_lds16(src + off, smem + off);
        }
    }
    // ---- stage x region: 80 chunks of 1KB = 4 x 256B segments each ----
    {
        const char* srcb = (const char*)xT;
        #pragma unroll
        for (int k = 0; k < 20; ++k) {
            const int chunk = w * 20 + k;            // 0..79
            const int seg   = chunk * 4 + (lane >> 4);   // 0..319 = bc*10+dhh
            const int bc    = seg / 10;
            const int dhh   = seg - bc * 10;
            const int dd_i  = (dhh >= 5) ? 1 : 0;
            const int hh_i  = dhh - dd_i * 5;
            const int dd = (qd - 1 + dd_i) & 15;
            const int hh = (qhq * 4 - 1 + hh_i) & 15;
            const long srcoff = ((long)bc * QV + (dd * 16 + hh) * 16 + (lane & 15)) * 16;
            gload_lds16(srcb + srcoff, x_lds + chunk * 1024 + lane * 16);
        }
    }
    asm volatile("s_waitcnt vmcnt(0)" ::: "memory");
    __syncthreads();

    // ---- compute: wave = batch; 2 tiles (tau) x 2 pw accs ----
    const int b    = w;
    const int n    = lane & 31;
    const int half = lane >> 5;
    const int qw   = n & 15;
    const int hsel = n >> 4;

    f32x16 acc00 = {}, acc01 = {};   // tau=0, pw=0/1
    f32x16 acc10 = {}, acc11 = {};   // tau=1, pw=0/1

    #pragma unroll
    for (int t = 0; t < 8; ++t) {
        const int td = t >> 2, th = (t >> 1) & 1, tw = t & 1;
        const int dd_i = 1 - td;
        const int ww = (qw - tw) & 15;
        const int hbase = dd_i * 5 + hsel + 1 - th;   // hh_i for tau=0
        #pragma unroll
        for (int ks = 0; ks < 4; ++ks) {
            const int c  = 2 * ks + half;
            const int bc = b * 8 + c;
            const s16x8 b0 = *reinterpret_cast<const s16x8*>(
                x_lds + (bc * 10 + hbase) * 256 + ww * 16);
            const s16x8 b1 = *reinterpret_cast<const s16x8*>(
                x_lds + (bc * 10 + hbase + 2) * 256 + ww * 16);
            const s16x8 a0 = *reinterpret_cast<const s16x8*>(
                we_lds + ((t * 8 + c) * 32 + n) * 8);
            const s16x8 a1 = *reinterpret_cast<const s16x8*>(
                we_lds + (((8 + t) * 8 + c) * 32 + n) * 8);
            acc00 = __builtin_amdgcn_mfma_f32_32x32x16_bf16(a0, b0, acc00, 0, 0, 0);
            acc01 = __builtin_amdgcn_mfma_f32_32x32x16_bf16(a1, b0, acc01, 0, 0, 0);
            acc10 = __builtin_amdgcn_mfma_f32_32x32x16_bf16(a0, b1, acc10, 0, 0, 0);
            acc11 = __builtin_amdgcn_mfma_f32_32x32x16_bf16(a1, b1, acc11, 0, 0, 0);
        }
    }

    // ---- store: D layout col n, row m=(r&3)+8*(r>>2)+4*half ----
    const int d = 2 * qd + pd;
    #pragma unroll
    for (int tau = 0; tau < 2; ++tau) {
        const int h = 2 * (4 * qhq + 2 * tau + hsel) + ph;
        float* ob = out + ((size_t)b * CO) * 32768 + d * 1024 + h * 32 + 2 * qw;
        #pragma unroll
        for (int r = 0; r < 16; ++r) {
            const int m = (r & 3) + 8 * (r >> 2) + 4 * half;
            float2 v;
            if (tau == 0) { v.x = acc00[r]; v.y = acc01[r]; }
            else          { v.x = acc10[r]; v.y = acc11[r]; }
            *reinterpret_cast<float2*>(ob + (size_t)m * 32768) = v;
        }
    }
}

extern "C" void kernel_launch(void* const* d_in, const int* in_sizes, int n_in,
                              void* d_out, int out_size, void* d_ws, size_t ws_size,
                              hipStream_t stream) {
    const float* x      = (const float*)d_in[0];
    const float* weight = (const float*)d_in[1];
    float* out          = (float*)d_out;

    unsigned short* xT = (unsigned short*)d_ws;
    unsigned short* We = xT + XT_ELEMS;

    prep_kernel<<<512, 256, 0, stream>>>(x, weight, xT, We);
    convt3d_mfma_kernel<<<256, 256, 0, stream>>>(xT, We, out);
}